// Round 7
// baseline (153.963 us; speedup 1.0000x reference)
//
#include <hip/hip_runtime.h>
#include <math.h>

// B=4, T=2048, N_EMBD=1024, HEAD=64.
// Reference multiplies scores by sqrt(64)=8; we fold 8*log2(e) into q and use exp2.
#define NE 1024
#define HS 64
#define TT 2048
#define QSC 11.541560327111707f   // 8 * log2(e)

typedef __bf16    v8bf __attribute__((ext_vector_type(8)));
typedef _Float16  v8h  __attribute__((ext_vector_type(8)));
typedef float     v4f  __attribute__((ext_vector_type(4)));

#define MFMA_BF(a, b, c)  __builtin_amdgcn_mfma_f32_16x16x32_bf16((a), (b), (c), 0, 0, 0)
#define MFMA_F16(a, b, c) __builtin_amdgcn_mfma_f32_16x16x32_f16((a), (b), (c), 0, 0, 0)

// async global->LDS DMA, 16 B per lane (lands at wave-uniform base + lane*16)
__device__ __forceinline__ void gl_lds16(const void* g, void* l) {
    __builtin_amdgcn_global_load_lds(
        (const __attribute__((address_space(1))) unsigned int*)g,
        (__attribute__((address_space(3))) unsigned int*)l, 16, 0, 0);
}

// ---------------------------------------------------------------------------
// prep_w: build the W "image" — hi/lo bf16, pre-arranged so that a linear
// global_load_lds stream lands B-fragments in LDS with an XOR-16B swizzle.
// Image layout (bytes): [step 0..31][ct 0..11][plane hi/lo][c 0..15][p16 0..3][16B]
//   content of (step,ct,pl,c,p16) = W[k = step*32 + (p16^(c&3))*8 + j][n = ct*16+c]
// ---------------------------------------------------------------------------
__global__ __launch_bounds__(256) void prep_w(
    const float* __restrict__ Wq, const float* __restrict__ Wk,
    const float* __restrict__ Wv, char* __restrict__ imgW)
{
    __shared__ float t[64][65];
    const int bx = blockIdx.x, by = blockIdx.y;
    const float* W = (by == 0) ? Wq : ((by == 1) ? Wk : Wv);
    const int tid = threadIdx.x;
    const int cc = tid & 63, r4 = tid >> 6;
    #pragma unroll
    for (int p = 0; p < 16; ++p) {
        const int k = p * 4 + r4;
        t[k][cc] = W[(size_t)(bx * 64 + k) * HS + cc];   // coalesced
    }
    __syncthreads();
    #pragma unroll
    for (int e = 0; e < 4; ++e) {
        const int chunk = tid + e * 256;
        const int s2   = chunk >> 9;
        const int rem  = chunk & 511;
        const int ctl  = rem >> 7;
        const int rem2 = rem & 127;
        const int pl   = rem2 >> 6;
        const int rem3 = rem2 & 63;
        const int c    = rem3 >> 2;
        const int p16  = rem3 & 3;
        const int kb   = s2 * 32 + ((p16 ^ (c & 3)) << 3);
        const int ncol = ctl * 16 + c;
        v8bf o;
        #pragma unroll
        for (int j = 0; j < 8; ++j) {
            const float v = t[kb + j][ncol];
            const __bf16 h = (__bf16)v;
            o[j] = pl ? (__bf16)(v - (float)h) : h;
        }
        *(v8bf*)(imgW + (size_t)(bx * 2 + s2) * 24576
                 + (by * 4 + ctl) * 2048 + pl * 1024 + c * 64 + p16 * 16) = o;
    }
}

// ---------------------------------------------------------------------------
// Projection GEMM: 512 blocks x 256 threads, block = 16 rows x all 192 cols,
// full K, 2 blocks/CU (second block computes through the first's barrier
// drain). Per BK=32 step, 26 KB staged async via global_load_lds (dbuf):
//   xbuf 2KB: [row 0..15][p32 0..3][32B], content chunk = p32 ^ (row&3)
//   wbuf 24KB: W image (above).  XOR swizzles keep b128 reads evenly banked.
// Waves: cg 0..3, each 48 cols x 16 rows -> 9 MFMA/step.
// ---------------------------------------------------------------------------
__global__ __launch_bounds__(256, 2) void proj(
    const float* __restrict__ x, const char* __restrict__ imgW,
    const float* __restrict__ bq, const float* __restrict__ bk,
    const float* __restrict__ bv,
    __bf16* __restrict__ qh, __bf16* __restrict__ ql,
    __bf16* __restrict__ kh, __bf16* __restrict__ kl,
    _Float16* __restrict__ vt)
{
    __shared__ __align__(16) char sbuf[2][26624];   // [buf][x 2KB | W 24KB]

    const int tid = threadIdx.x, lane = tid & 63, cg = tid >> 6;
    const int quad = lane >> 4, l16 = lane & 15;
    const int m0 = blockIdx.x * 16;

    const int xrow = tid >> 3;                       // tid<128: rows 0..15
    const int xc32 = ((tid & 7) >> 1) ^ (xrow & 3);
    const float* gx = x + (size_t)(m0 + xrow) * NE + xc32 * 8 + (tid & 1) * 4;
    const char*  gw = imgW + (size_t)tid * 16;

    v4f acc[3];
    #pragma unroll
    for (int i = 0; i < 3; ++i) acc[i] = (v4f){0.f, 0.f, 0.f, 0.f};

    #define STAGE(ks, b)  do {                                           \
        char* xb_ = sbuf[(b)];                                           \
        if (tid < 128) gl_lds16(gx + (ks) * 32, xb_ + tid * 16);         \
        const char* gws_ = gw + (size_t)(ks) * 24576;                    \
        _Pragma("unroll")                                                \
        for (int j_ = 0; j_ < 6; ++j_)                                   \
            gl_lds16(gws_ + j_ * 4096, xb_ + 2048 + tid * 16 + j_ * 4096); \
    } while (0)

    STAGE(0, 0);
    __syncthreads();

    for (int ks = 0; ks < 32; ++ks) {
        const int b = ks & 1;
        if (ks < 31) STAGE(ks + 1, b ^ 1);

        const char* xb = sbuf[b];
        const char* wb = xb + 2048;
        const int rl = l16;
        const int pA = quad ^ (rl & 3);
        const float4 a0 = *(const float4*)(xb + rl * 128 + pA * 32);
        const float4 a1 = *(const float4*)(xb + rl * 128 + pA * 32 + 16);
        const float av[8] = {a0.x, a0.y, a0.z, a0.w, a1.x, a1.y, a1.z, a1.w};
        v8bf ah, al;
        #pragma unroll
        for (int i = 0; i < 8; ++i) {
            const __bf16 h = (__bf16)av[i];
            ah[i] = h;
            al[i] = (__bf16)(av[i] - (float)h);
        }
        const int wo = l16 * 64 + ((quad ^ (l16 & 3)) << 4);
        #pragma unroll
        for (int j = 0; j < 3; ++j) {
            const char* base = wb + (cg * 3 + j) * 2048 + wo;
            const v8bf bh = *(const v8bf*)(base);
            const v8bf bl = *(const v8bf*)(base + 1024);
            acc[j] = MFMA_BF(ah, bh, acc[j]);
            acc[j] = MFMA_BF(ah, bl, acc[j]);
            acc[j] = MFMA_BF(al, bh, acc[j]);
        }
        __syncthreads();
    }
    #undef STAGE

    // epilogue: C layout col=l16 (within n-tile), row=quad*4+reg
    #pragma unroll
    for (int j = 0; j < 3; ++j) {
        const int n = cg * 48 + j * 16 + l16;
        const float bias = (n < 64) ? bq[n] : ((n < 128) ? bk[n - 64] : bv[n - 128]);
        #pragma unroll
        for (int reg = 0; reg < 4; ++reg) {
            const int row = m0 + quad * 4 + reg;
            const float v = acc[j][reg] + bias;
            if (n < 64) {
                const float s = v * QSC;             // fold 8*log2e into q
                const __bf16 hh = (__bf16)s;
                qh[(size_t)row * HS + n] = hh;
                ql[(size_t)row * HS + n] = (__bf16)(s - (float)hh);
            } else if (n < 128) {
                const __bf16 hh = (__bf16)v;
                kh[(size_t)row * HS + n - 64] = hh;
                kl[(size_t)row * HS + n - 64] = (__bf16)(v - (float)hh);
            } else {
                const int b2 = row >> 11, tt = row & 2047, hc = n - 128;
                vt[((size_t)(b2 * HS + hc)) * TT + tt] = (_Float16)v;
            }
        }
    }
}

// ---------------------------------------------------------------------------
// Flash attention, MFMA, K-fragment double buffering: K(t+4) prefetch issued
// right after QK(t) consumes the current buffer; V single-buffered (covered
// by QK+softmax). Block = 16 q-rows, 4 waves key-split, exp2 softmax,
// ones-column row sums, merge via LDS.
// ---------------------------------------------------------------------------
__global__ __launch_bounds__(256, 2) void attn(
    const __bf16* __restrict__ qh, const __bf16* __restrict__ ql,
    const __bf16* __restrict__ kh, const __bf16* __restrict__ kl,
    const _Float16* __restrict__ vt, float* __restrict__ out)
{
    __shared__ __align__(16) char smem_raw[4 * 16 * 68 * 4];  // 17408 B
    _Float16* ps = (_Float16*)smem_raw;   // [w][16*72] fp16 (k-loop only)
    float*    os = (float*)smem_raw;      // [w][16*68] fp32 (merge only)
    __shared__ float sm[4][16], sl[4][16];

    const int tid = threadIdx.x, lane = tid & 63, w = tid >> 6;
    const int quad = lane >> 4, l16 = lane & 15;
    const int b = blockIdx.x & 3, qi = blockIdx.x >> 2;
    const int q0 = (127 - qi) * 16;                 // heavy tiles first

    const size_t qrow = ((size_t)b * TT + q0 + l16) * HS;
    const v8bf Qh0 = *(const v8bf*)(qh + qrow + quad * 8);
    const v8bf Qh1 = *(const v8bf*)(qh + qrow + 32 + quad * 8);
    const v8bf Ql0 = *(const v8bf*)(ql + qrow + quad * 8);
    const v8bf Ql1 = *(const v8bf*)(ql + qrow + 32 + quad * 8);

    const v8h vones = {(_Float16)1.f, (_Float16)1.f, (_Float16)1.f, (_Float16)1.f,
                       (_Float16)1.f, (_Float16)1.f, (_Float16)1.f, (_Float16)1.f};

    float mrow[4] = {-3e38f, -3e38f, -3e38f, -3e38f};
    v4f o[4], o4;
    #pragma unroll
    for (int i = 0; i < 4; ++i) o[i] = (v4f){0.f, 0.f, 0.f, 0.f};
    o4 = (v4f){0.f, 0.f, 0.f, 0.f};

    const int irow = q0 + quad * 4;                 // + reg
    const int ntk = (q0 + 16 + 63) >> 6;
    _Float16* pw = ps + w * (16 * 72);

    auto loadK = [&](v8bf (&Kh_)[8], v8bf (&Kl_)[8], int j0) {
        #pragma unroll
        for (int nt = 0; nt < 4; ++nt) {
            const size_t krow = ((size_t)b * TT + j0 + nt * 16 + l16) * HS;
            Kh_[nt * 2]     = *(const v8bf*)(kh + krow + quad * 8);
            Kh_[nt * 2 + 1] = *(const v8bf*)(kh + krow + 32 + quad * 8);
            Kl_[nt * 2]     = *(const v8bf*)(kl + krow + quad * 8);
            Kl_[nt * 2 + 1] = *(const v8bf*)(kl + krow + 32 + quad * 8);
        }
    };
    auto loadV = [&](v8h (&Vf_)[8], int j0) {
        #pragma unroll
        for (int nt = 0; nt < 4; ++nt) {
            const size_t vrow = ((size_t)(b * HS + nt * 16 + l16)) * TT + j0;
            Vf_[nt * 2]     = *(const v8h*)(vt + vrow + quad * 8);
            Vf_[nt * 2 + 1] = *(const v8h*)(vt + vrow + 32 + quad * 8);
        }
    };
    auto qkmm = [&](v8bf (&Kh_)[8], v8bf (&Kl_)[8], v4f (&s)[4]) {
        #pragma unroll
        for (int i = 0; i < 4; ++i) s[i] = (v4f){0.f, 0.f, 0.f, 0.f};
        #pragma unroll
        for (int nt = 0; nt < 4; ++nt) {
            s[nt] = MFMA_BF(Qh0, Kh_[nt * 2],     s[nt]);
            s[nt] = MFMA_BF(Qh1, Kh_[nt * 2 + 1], s[nt]);
            s[nt] = MFMA_BF(Qh0, Kl_[nt * 2],     s[nt]);
            s[nt] = MFMA_BF(Qh1, Kl_[nt * 2 + 1], s[nt]);
            s[nt] = MFMA_BF(Ql0, Kh_[nt * 2],     s[nt]);
            s[nt] = MFMA_BF(Ql1, Kh_[nt * 2 + 1], s[nt]);
        }
    };
    auto smaxpv = [&](v4f (&s)[4], v8h (&Vf_)[8], int j0) {
        float mx[4] = {-3e38f, -3e38f, -3e38f, -3e38f};
        #pragma unroll
        for (int nt = 0; nt < 4; ++nt)
            #pragma unroll
            for (int reg = 0; reg < 4; ++reg) {
                if (j0 + nt * 16 + l16 > irow + reg) s[nt][reg] = -3e38f;
                mx[reg] = fmaxf(mx[reg], s[nt][reg]);
            }
        #pragma unroll
        for (int off = 8; off; off >>= 1)
            #pragma unroll
            for (int reg = 0; reg < 4; ++reg)
                mx[reg] = fmaxf(mx[reg], __shfl_xor(mx[reg], off));
        float al[4];
        #pragma unroll
        for (int reg = 0; reg < 4; ++reg) {
            const float mn = fmaxf(mrow[reg], mx[reg]);
            al[reg] = exp2f(mrow[reg] - mn);
            mrow[reg] = mn;
        }
        #pragma unroll
        for (int nt = 0; nt < 4; ++nt)
            #pragma unroll
            for (int reg = 0; reg < 4; ++reg) {
                const float p = (j0 + nt * 16 + l16 > irow + reg)
                                    ? 0.f : exp2f(s[nt][reg] - mrow[reg]);
                pw[(quad * 4 + reg) * 72 + nt * 16 + l16] = (_Float16)p;
            }
        #pragma unroll
        for (int nt = 0; nt < 4; ++nt)
            #pragma unroll
            for (int reg = 0; reg < 4; ++reg)
                o[nt][reg] *= al[reg];
        #pragma unroll
        for (int reg = 0; reg < 4; ++reg)
            o4[reg] *= al[reg];
        v8h Pa0 = *(const v8h*)(pw + l16 * 72 + quad * 8);
        v8h Pa1 = *(const v8h*)(pw + l16 * 72 + 32 + quad * 8);
        #pragma unroll
        for (int nt = 0; nt < 4; ++nt) {
            o[nt] = MFMA_F16(Pa0, Vf_[nt * 2],     o[nt]);
            o[nt] = MFMA_F16(Pa1, Vf_[nt * 2 + 1], o[nt]);
        }
        o4 = MFMA_F16(Pa0, vones, o4);
        o4 = MFMA_F16(Pa1, vones, o4);
    };

    v8bf KhA[8], KlA[8], KhB[8], KlB[8];
    v8h  Vf[8];
    v4f  s[4];

    int t = w;
    if (t < ntk) {
        loadK(KhA, KlA, t * 64);
        for (;;) {
            // phase A
            loadV(Vf, t * 64);
            qkmm(KhA, KlA, s);
            if (t + 4 < ntk) loadK(KhB, KlB, (t + 4) * 64);
            smaxpv(s, Vf, t * 64);
            t += 4;
            if (t >= ntk) break;
            // phase B
            loadV(Vf, t * 64);
            qkmm(KhB, KlB, s);
            if (t + 4 < ntk) loadK(KhA, KlA, (t + 4) * 64);
            smaxpv(s, Vf, t * 64);
            t += 4;
            if (t >= ntk) break;
        }
    }

    // merge the 4 key-split waves
    if (l16 == 0) {
        #pragma unroll
        for (int reg = 0; reg < 4; ++reg) {
            sm[w][quad * 4 + reg] = mrow[reg];
            sl[w][quad * 4 + reg] = o4[reg];
        }
    }
    __syncthreads();
    float sc[4];
    #pragma unroll
    for (int reg = 0; reg < 4; ++reg) {
        const int r = quad * 4 + reg;
        float M = sm[0][r];
        #pragma unroll
        for (int i = 1; i < 4; ++i) M = fmaxf(M, sm[i][r]);
        sc[reg] = exp2f(mrow[reg] - M);
    }
    float* ow = os + w * (16 * 68);
    #pragma unroll
    for (int nt = 0; nt < 4; ++nt)
        #pragma unroll
        for (int reg = 0; reg < 4; ++reg)
            ow[(quad * 4 + reg) * 68 + nt * 16 + l16] = o[nt][reg] * sc[reg];
    __syncthreads();

    #pragma unroll
    for (int kk = 0; kk < 4; ++kk) {
        const int m = w * 4 + kk;
        float M = sm[0][m];
        #pragma unroll
        for (int i = 1; i < 4; ++i) M = fmaxf(M, sm[i][m]);
        float L = 0.f, val = 0.f;
        #pragma unroll
        for (int i = 0; i < 4; ++i) {
            L   += sl[i][m] * exp2f(sm[i][m] - M);
            val += os[i * (16 * 68) + m * 68 + lane];
        }
        out[((size_t)b * TT + q0 + m) * HS + lane] = val / L;
    }
}

// ---------------------------------------------------------------------------
extern "C" void kernel_launch(void* const* d_in, const int* in_sizes, int n_in,
                              void* d_out, int out_size, void* d_ws, size_t ws_size,
                              hipStream_t stream)
{
    const float* x  = (const float*)d_in[0];
    const float* Wq = (const float*)d_in[1];
    const float* bq = (const float*)d_in[2];
    const float* Wk = (const float*)d_in[3];
    const float* bk = (const float*)d_in[4];
    const float* Wv = (const float*)d_in[5];
    const float* bv = (const float*)d_in[6];
    float* out = (float*)d_out;

    const int rows = in_sizes[0] / NE;   // 8192
    char* p = (char*)d_ws;
    char* imgW = p;                           p += (size_t)32 * 24576;      // 768 KB
    __bf16* qhb = (__bf16*)p;                 p += (size_t)rows * HS * 2;
    __bf16* qlb = (__bf16*)p;                 p += (size_t)rows * HS * 2;
    __bf16* khb = (__bf16*)p;                 p += (size_t)rows * HS * 2;
    __bf16* klb = (__bf16*)p;                 p += (size_t)rows * HS * 2;
    _Float16* vtb = (_Float16*)p;             p += (size_t)rows * HS * 2;

    prep_w<<<dim3(16, 3), 256, 0, stream>>>(Wq, Wk, Wv, imgW);
    proj<<<rows / 16, 256, 0, stream>>>(x, imgW, bq, bk, bv,
                                        qhb, qlb, khb, klb, vtb);
    attn<<<rows / 16, 256, 0, stream>>>(qhb, qlb, khb, klb, vtb, out);
}

// Round 9
// 138.665 us; speedup vs baseline: 1.1103x; 1.1103x over previous
//
#include <hip/hip_runtime.h>
#include <math.h>

// B=4, T=2048, N_EMBD=1024, HEAD=64.
// Reference multiplies scores by sqrt(64)=8; we fold 8*log2(e) into q and use exp2.
#define NE 1024
#define HS 64
#define TT 2048
#define QSC 11.541560327111707f   // 8 * log2(e)

typedef __bf16    v8bf __attribute__((ext_vector_type(8)));
typedef _Float16  v8h  __attribute__((ext_vector_type(8)));
typedef float     v4f  __attribute__((ext_vector_type(4)));

#define MFMA_BF(a, b, c)  __builtin_amdgcn_mfma_f32_16x16x32_bf16((a), (b), (c), 0, 0, 0)
#define MFMA_F16(a, b, c) __builtin_amdgcn_mfma_f32_16x16x32_f16((a), (b), (c), 0, 0, 0)

// async global->LDS DMA, 16 B per lane (lands at wave-uniform base + lane*16)
__device__ __forceinline__ void gl_lds16(const void* g, void* l) {
    __builtin_amdgcn_global_load_lds(
        (const __attribute__((address_space(1))) unsigned int*)g,
        (__attribute__((address_space(3))) unsigned int*)l, 16, 0, 0);
}

// ---------------------------------------------------------------------------
// prep_w: build the W "image" — hi/lo bf16, pre-arranged so that a linear
// global_load_lds stream lands B-fragments in LDS with an XOR-16B swizzle.
// ---------------------------------------------------------------------------
__global__ __launch_bounds__(256) void prep_w(
    const float* __restrict__ Wq, const float* __restrict__ Wk,
    const float* __restrict__ Wv, char* __restrict__ imgW)
{
    __shared__ float t[64][65];
    const int bx = blockIdx.x, by = blockIdx.y;
    const float* W = (by == 0) ? Wq : ((by == 1) ? Wk : Wv);
    const int tid = threadIdx.x;
    const int cc = tid & 63, r4 = tid >> 6;
    #pragma unroll
    for (int p = 0; p < 16; ++p) {
        const int k = p * 4 + r4;
        t[k][cc] = W[(size_t)(bx * 64 + k) * HS + cc];   // coalesced
    }
    __syncthreads();
    #pragma unroll
    for (int e = 0; e < 4; ++e) {
        const int chunk = tid + e * 256;
        const int s2   = chunk >> 9;
        const int rem  = chunk & 511;
        const int ctl  = rem >> 7;
        const int rem2 = rem & 127;
        const int pl   = rem2 >> 6;
        const int rem3 = rem2 & 63;
        const int c    = rem3 >> 2;
        const int p16  = rem3 & 3;
        const int kb   = s2 * 32 + ((p16 ^ (c & 3)) << 3);
        const int ncol = ctl * 16 + c;
        v8bf o;
        #pragma unroll
        for (int j = 0; j < 8; ++j) {
            const float v = t[kb + j][ncol];
            const __bf16 h = (__bf16)v;
            o[j] = pl ? (__bf16)(v - (float)h) : h;
        }
        *(v8bf*)(imgW + (size_t)(bx * 2 + s2) * 24576
                 + (by * 4 + ctl) * 2048 + pl * 1024 + c * 64 + p16 * 16) = o;
    }
}

// ---------------------------------------------------------------------------
// Projection GEMM (round-7 structure): 512 blocks x 256 thr, block = 16 rows
// x 192 cols, full K, async-DMA double-buffered staging, 2 blocks/CU.
// Epilogue: q (x QSC) hi/lo bf16, k hi/lo bf16, v^T fp16.
// ---------------------------------------------------------------------------
__global__ __launch_bounds__(256, 2) void proj(
    const float* __restrict__ x, const char* __restrict__ imgW,
    const float* __restrict__ bq, const float* __restrict__ bk,
    const float* __restrict__ bv,
    __bf16* __restrict__ qh, __bf16* __restrict__ ql,
    __bf16* __restrict__ kh, __bf16* __restrict__ kl,
    _Float16* __restrict__ vt)
{
    __shared__ __align__(16) char sbuf[2][26624];   // [buf][x 2KB | W 24KB]

    const int tid = threadIdx.x, lane = tid & 63, cg = tid >> 6;
    const int quad = lane >> 4, l16 = lane & 15;
    const int m0 = blockIdx.x * 16;

    const int xrow = tid >> 3;                       // tid<128: rows 0..15
    const int xc32 = ((tid & 7) >> 1) ^ (xrow & 3);
    const float* gx = x + (size_t)(m0 + xrow) * NE + xc32 * 8 + (tid & 1) * 4;
    const char*  gw = imgW + (size_t)tid * 16;

    v4f acc[3];
    #pragma unroll
    for (int i = 0; i < 3; ++i) acc[i] = (v4f){0.f, 0.f, 0.f, 0.f};

    #define STAGE(ks, b)  do {                                           \
        char* xb_ = sbuf[(b)];                                           \
        if (tid < 128) gl_lds16(gx + (ks) * 32, xb_ + tid * 16);         \
        const char* gws_ = gw + (size_t)(ks) * 24576;                    \
        _Pragma("unroll")                                                \
        for (int j_ = 0; j_ < 6; ++j_)                                   \
            gl_lds16(gws_ + j_ * 4096, xb_ + 2048 + tid * 16 + j_ * 4096); \
    } while (0)

    STAGE(0, 0);
    __syncthreads();

    for (int ks = 0; ks < 32; ++ks) {
        const int b = ks & 1;
        if (ks < 31) STAGE(ks + 1, b ^ 1);

        const char* xb = sbuf[b];
        const char* wb = xb + 2048;
        const int rl = l16;
        const int pA = quad ^ (rl & 3);
        const float4 a0 = *(const float4*)(xb + rl * 128 + pA * 32);
        const float4 a1 = *(const float4*)(xb + rl * 128 + pA * 32 + 16);
        const float av[8] = {a0.x, a0.y, a0.z, a0.w, a1.x, a1.y, a1.z, a1.w};
        v8bf ah, al;
        #pragma unroll
        for (int i = 0; i < 8; ++i) {
            const __bf16 h = (__bf16)av[i];
            ah[i] = h;
            al[i] = (__bf16)(av[i] - (float)h);
        }
        const int wo = l16 * 64 + ((quad ^ (l16 & 3)) << 4);
        #pragma unroll
        for (int j = 0; j < 3; ++j) {
            const char* base = wb + (cg * 3 + j) * 2048 + wo;
            const v8bf bh = *(const v8bf*)(base);
            const v8bf bl = *(const v8bf*)(base + 1024);
            acc[j] = MFMA_BF(ah, bh, acc[j]);
            acc[j] = MFMA_BF(ah, bl, acc[j]);
            acc[j] = MFMA_BF(al, bh, acc[j]);
        }
        __syncthreads();
    }
    #undef STAGE

    // epilogue: C layout col=l16 (within n-tile), row=quad*4+reg
    #pragma unroll
    for (int j = 0; j < 3; ++j) {
        const int n = cg * 48 + j * 16 + l16;
        const float bias = (n < 64) ? bq[n] : ((n < 128) ? bk[n - 64] : bv[n - 128]);
        #pragma unroll
        for (int reg = 0; reg < 4; ++reg) {
            const int row = m0 + quad * 4 + reg;
            const float v = acc[j][reg] + bias;
            if (n < 64) {
                const float s = v * QSC;             // fold 8*log2e into q
                const __bf16 hh = (__bf16)s;
                qh[(size_t)row * HS + n] = hh;
                ql[(size_t)row * HS + n] = (__bf16)(s - (float)hh);
            } else if (n < 128) {
                const __bf16 hh = (__bf16)v;
                kh[(size_t)row * HS + n - 64] = hh;
                kl[(size_t)row * HS + n - 64] = (__bf16)(v - (float)hh);
            } else {
                const int b2 = row >> 11, tt = row & 2047, hc = n - 128;
                vt[((size_t)(b2 * HS + hc)) * TT + tt] = (_Float16)v;
            }
        }
    }
}

// ---------------------------------------------------------------------------
// Flash attention, split-precision bf16 QK + fp16 PV, balanced pair grid:
// block = q-tile PAIR (qi, 127-qi) -> combined key-chunk count = 33 for every
// block. 256 blocks x 512 threads (1/CU, 8 waves); waves round-robin the
// combined chunk list (<=5 chunks each, uniform chip-wide). Per-wave dual
// (m, o, l) state; single batched K+V load wall per chunk; exp2 softmax;
// ones-column row sums; 2-stage LDS merge.
// ---------------------------------------------------------------------------
__global__ __launch_bounds__(512, 2) void attn(
    const __bf16* __restrict__ qh, const __bf16* __restrict__ ql,
    const __bf16* __restrict__ kh, const __bf16* __restrict__ kl,
    const _Float16* __restrict__ vt, float* __restrict__ out)
{
    // union: P buffers (8 waves x 16x72 fp16 = 36864 B) during the loop,
    // merge slabs (16 x 16x68 fp32 = 69632 B) afterwards.
    __shared__ __align__(16) char smem_raw[69632];
    _Float16* ps = (_Float16*)smem_raw;
    float*    os = (float*)smem_raw;
    __shared__ float sm[8][2][16], sl[8][2][16];

    const int tid = threadIdx.x, lane = tid & 63, w = tid >> 6;
    const int quad = lane >> 4, l16 = lane & 15;
    const int b = blockIdx.x & 3, pair = blockIdx.x >> 2;   // pair 0..63
    const int q0t[2] = {(127 - pair) * 16, pair * 16};
    const int ntk0 = (q0t[0] + 16 + 63) >> 6;
    const int ntk1 = (q0t[1] + 16 + 63) >> 6;
    const int total = ntk0 + ntk1;                          // == 33

    // Q fragments (hi/lo) for both tiles
    v8bf Qh0[2], Qh1[2], Ql0[2], Ql1[2];
    #pragma unroll
    for (int t = 0; t < 2; ++t) {
        const size_t qrow = ((size_t)b * TT + q0t[t] + l16) * HS;
        Qh0[t] = *(const v8bf*)(qh + qrow + quad * 8);
        Qh1[t] = *(const v8bf*)(qh + qrow + 32 + quad * 8);
        Ql0[t] = *(const v8bf*)(ql + qrow + quad * 8);
        Ql1[t] = *(const v8bf*)(ql + qrow + 32 + quad * 8);
    }

    const v8h vones = {(_Float16)1.f, (_Float16)1.f, (_Float16)1.f, (_Float16)1.f,
                       (_Float16)1.f, (_Float16)1.f, (_Float16)1.f, (_Float16)1.f};

    float mr0[4] = {-3e38f, -3e38f, -3e38f, -3e38f};
    float mr1[4] = {-3e38f, -3e38f, -3e38f, -3e38f};
    v4f o0[4], o1[4], l40, l41;
    #pragma unroll
    for (int i = 0; i < 4; ++i) {
        o0[i] = (v4f){0.f, 0.f, 0.f, 0.f};
        o1[i] = (v4f){0.f, 0.f, 0.f, 0.f};
    }
    l40 = (v4f){0.f, 0.f, 0.f, 0.f};
    l41 = (v4f){0.f, 0.f, 0.f, 0.f};

    _Float16* pw = ps + w * (16 * 72);

    auto doChunk = [&](int j0, int q0c, int t,
                       float (&mrow)[4], v4f (&o)[4], v4f &o4) {
        v8bf Kh[8], Kl[8];
        v8h  Vf[8];
        #pragma unroll
        for (int nt = 0; nt < 4; ++nt) {
            const size_t krow = ((size_t)b * TT + j0 + nt * 16 + l16) * HS;
            Kh[nt * 2]     = *(const v8bf*)(kh + krow + quad * 8);
            Kh[nt * 2 + 1] = *(const v8bf*)(kh + krow + 32 + quad * 8);
            Kl[nt * 2]     = *(const v8bf*)(kl + krow + quad * 8);
            Kl[nt * 2 + 1] = *(const v8bf*)(kl + krow + 32 + quad * 8);
        }
        #pragma unroll
        for (int nt = 0; nt < 4; ++nt) {
            const size_t vrow = ((size_t)(b * HS + nt * 16 + l16)) * TT + j0;
            Vf[nt * 2]     = *(const v8h*)(vt + vrow + quad * 8);
            Vf[nt * 2 + 1] = *(const v8h*)(vt + vrow + 32 + quad * 8);
        }
        v4f s[4];
        #pragma unroll
        for (int i = 0; i < 4; ++i) s[i] = (v4f){0.f, 0.f, 0.f, 0.f};
        #pragma unroll
        for (int nt = 0; nt < 4; ++nt) {
            s[nt] = MFMA_BF(Qh0[t], Kh[nt * 2],     s[nt]);
            s[nt] = MFMA_BF(Qh1[t], Kh[nt * 2 + 1], s[nt]);
            s[nt] = MFMA_BF(Qh0[t], Kl[nt * 2],     s[nt]);
            s[nt] = MFMA_BF(Qh1[t], Kl[nt * 2 + 1], s[nt]);
            s[nt] = MFMA_BF(Ql0[t], Kh[nt * 2],     s[nt]);
            s[nt] = MFMA_BF(Ql1[t], Kh[nt * 2 + 1], s[nt]);
        }
        const int irow = q0c + quad * 4;
        float mx[4] = {-3e38f, -3e38f, -3e38f, -3e38f};
        #pragma unroll
        for (int nt = 0; nt < 4; ++nt)
            #pragma unroll
            for (int reg = 0; reg < 4; ++reg) {
                if (j0 + nt * 16 + l16 > irow + reg) s[nt][reg] = -3e38f;
                mx[reg] = fmaxf(mx[reg], s[nt][reg]);
            }
        #pragma unroll
        for (int off = 8; off; off >>= 1)
            #pragma unroll
            for (int reg = 0; reg < 4; ++reg)
                mx[reg] = fmaxf(mx[reg], __shfl_xor(mx[reg], off));
        float al[4];
        #pragma unroll
        for (int reg = 0; reg < 4; ++reg) {
            const float mn = fmaxf(mrow[reg], mx[reg]);
            al[reg] = exp2f(mrow[reg] - mn);
            mrow[reg] = mn;
        }
        #pragma unroll
        for (int nt = 0; nt < 4; ++nt)
            #pragma unroll
            for (int reg = 0; reg < 4; ++reg) {
                const float p = (j0 + nt * 16 + l16 > irow + reg)
                                    ? 0.f : exp2f(s[nt][reg] - mrow[reg]);
                pw[(quad * 4 + reg) * 72 + nt * 16 + l16] = (_Float16)p;
            }
        #pragma unroll
        for (int nt = 0; nt < 4; ++nt)
            #pragma unroll
            for (int reg = 0; reg < 4; ++reg)
                o[nt][reg] *= al[reg];
        #pragma unroll
        for (int reg = 0; reg < 4; ++reg)
            o4[reg] *= al[reg];
        const v8h Pa0 = *(const v8h*)(pw + l16 * 72 + quad * 8);
        const v8h Pa1 = *(const v8h*)(pw + l16 * 72 + 32 + quad * 8);
        #pragma unroll
        for (int nt = 0; nt < 4; ++nt) {
            o[nt] = MFMA_F16(Pa0, Vf[nt * 2],     o[nt]);
            o[nt] = MFMA_F16(Pa1, Vf[nt * 2 + 1], o[nt]);
        }
        o4 = MFMA_F16(Pa0, vones, o4);
        o4 = MFMA_F16(Pa1, vones, o4);
    };

    for (int c = w; c < total; c += 8) {
        if (c < ntk0) doChunk(c * 64,          q0t[0], 0, mr0, o0, l40);
        else          doChunk((c - ntk0) * 64, q0t[1], 1, mr1, o1, l41);
    }

    // stage 1: per-wave per-tile state to LDS
    if (l16 == 0) {
        #pragma unroll
        for (int reg = 0; reg < 4; ++reg) {
            sm[w][0][quad * 4 + reg] = mr0[reg];
            sl[w][0][quad * 4 + reg] = l40[reg];
            sm[w][1][quad * 4 + reg] = mr1[reg];
            sl[w][1][quad * 4 + reg] = l41[reg];
        }
    }
    __syncthreads();   // also fences last ps reads before os overwrite

    // stage 2: rescale own O by exp2(m_w - M) and write merge slabs
    #pragma unroll
    for (int t = 0; t < 2; ++t) {
        float sc[4];
        #pragma unroll
        for (int reg = 0; reg < 4; ++reg) {
            const int r = quad * 4 + reg;
            float M = sm[0][t][r];
            #pragma unroll
            for (int i = 1; i < 8; ++i) M = fmaxf(M, sm[i][t][r]);
            const float mw = t ? mr1[reg] : mr0[reg];
            sc[reg] = exp2f(mw - M);
        }
        float* ow = os + (size_t)(w * 2 + t) * (16 * 68);
        #pragma unroll
        for (int nt = 0; nt < 4; ++nt)
            #pragma unroll
            for (int reg = 0; reg < 4; ++reg) {
                const v4f& oo = t ? o1[nt] : o0[nt];
                ow[(quad * 4 + reg) * 68 + nt * 16 + l16] = oo[reg] * sc[reg];
            }
    }
    __syncthreads();

    // stage 3: sum the 8 wave slabs, divide, store. 32 rows over 8 waves.
    #pragma unroll
    for (int kk = 0; kk < 4; ++kk) {
        const int g = w * 4 + kk;
        const int t = g >> 4, m = g & 15;
        float M = sm[0][t][m];
        #pragma unroll
        for (int i = 1; i < 8; ++i) M = fmaxf(M, sm[i][t][m]);
        float L = 0.f, val = 0.f;
        #pragma unroll
        for (int i = 0; i < 8; ++i) {
            L   += sl[i][t][m] * exp2f(sm[i][t][m] - M);
            val += os[(size_t)(i * 2 + t) * (16 * 68) + m * 68 + lane];
        }
        out[((size_t)b * TT + q0t[t] + m) * HS + lane] = val / L;
    }
}

// ---------------------------------------------------------------------------
extern "C" void kernel_launch(void* const* d_in, const int* in_sizes, int n_in,
                              void* d_out, int out_size, void* d_ws, size_t ws_size,
                              hipStream_t stream)
{
    const float* x  = (const float*)d_in[0];
    const float* Wq = (const float*)d_in[1];
    const float* bq = (const float*)d_in[2];
    const float* Wk = (const float*)d_in[3];
    const float* bk = (const float*)d_in[4];
    const float* Wv = (const float*)d_in[5];
    const float* bv = (const float*)d_in[6];
    float* out = (float*)d_out;

    const int rows = in_sizes[0] / NE;   // 8192
    char* p = (char*)d_ws;
    char* imgW = p;                           p += (size_t)32 * 24576;      // 768 KB
    __bf16* qhb = (__bf16*)p;                 p += (size_t)rows * HS * 2;
    __bf16* qlb = (__bf16*)p;                 p += (size_t)rows * HS * 2;
    __bf16* khb = (__bf16*)p;                 p += (size_t)rows * HS * 2;
    __bf16* klb = (__bf16*)p;                 p += (size_t)rows * HS * 2;
    _Float16* vtb = (_Float16*)p;             p += (size_t)rows * HS * 2;

    prep_w<<<dim3(16, 3), 256, 0, stream>>>(Wq, Wk, Wv, imgW);
    proj<<<rows / 16, 256, 0, stream>>>(x, imgW, bq, bk, bv,
                                        qhb, qlb, khb, klb, vtb);
    attn<<<rows / 32, 512, 0, stream>>>(qhb, qlb, khb, klb, vtb, out);
}